// Round 2
// baseline (134.967 us; speedup 1.0000x reference)
//
#include <hip/hip_runtime.h>
#include <math.h>

#define T_WAV    8388608
#define FRAME_L  1024
#define HOP      256
#define NF       32765   // (T_WAV - FRAME_L)/HOP + 1

// ---------------------------------------------------------------------------
// Mask layout detection: the harness's pristine-restore may leave voiced_mask
// as either int32 0/1 per frame (4 B/elt) or packed bool bytes (1 B/elt).
// int32 0/1 words never have nonzero bytes 1..3; packed-bool words almost
// surely do (p≈0.992 per word at 80% voiced). Reading a single byte at offset
// (bytelay ? f : 4*f) is correct for BOTH layouts (little-endian low byte).
// ---------------------------------------------------------------------------
__device__ __forceinline__ bool detect_byte_layout(const unsigned int* mask_words,
                                                   int tid) {
    __shared__ int s_flag;
    if (tid == 0) s_flag = 0;
    __syncthreads();
    unsigned w = mask_words[tid & 255];          // first 1 KB, L2-hot
    if ((w & 0xFFFFFF00u) != 0u && w != 0xFFFFFFFFu) atomicOr(&s_flag, 1);
    __syncthreads();
    return s_flag != 0;
}

// Prepass: per-frame {enc = valid ? new_len : -1, scale} + hann[1024] table.
__global__ __launch_bounds__(256) void psola_prepass(
    const float* __restrict__ src_f0,
    const float* __restrict__ tgt_f0,
    const unsigned int* __restrict__ mask_words,
    float* __restrict__ hann_t,     // [1024]
    float* __restrict__ scale_t,    // [32768]
    int*   __restrict__ enc_t)      // [32768]
{
    bool bytelay = detect_byte_layout(mask_words, threadIdx.x);

    if (blockIdx.x == 0) {
        for (int k = threadIdx.x; k < 1024; k += 256)
            hann_t[k] = 0.5f - 0.5f * cospif((float)k * (1.0f / 512.0f));
    }

    int f = blockIdx.x * 256 + threadIdx.x;
    if (f < NF) {
        float src = src_f0[f];
        float tgt = tgt_f0[f];
        const unsigned char* m8 = (const unsigned char*)mask_words;
        unsigned off = bytelay ? (unsigned)f : ((unsigned)f << 2);
        int vm = m8[off];
        bool valid = (vm != 0) && (src >= 1.0f) && (tgt >= 1.0f);
        float denom = (tgt >= 1.0f) ? tgt : 1.0f;
        float ratio = fminf(fmaxf(src / denom, 0.25f), 4.0f);
        int nl = (int)rintf(1024.0f * ratio);    // round-half-even == jnp.round
        if (nl < 1) nl = 1;
        scale_t[f] = 1024.0f / (float)nl;
        enc_t[f]   = valid ? nl : -1;
    }
}

// Main: gather formulation — each output sample sums its <=4 covering frames.
__global__ __launch_bounds__(256) void psola_main(
    const float* __restrict__ wav,
    const float* __restrict__ hann_t,
    const float* __restrict__ scale_t,
    const int*   __restrict__ enc_t,
    float*       __restrict__ out)
{
    int t = blockIdx.x * 256 + threadIdx.x;      // grid covers T_WAV exactly

    int a    = t - (FRAME_L - 1);
    int f_lo = (a > 0) ? ((a + HOP - 1) >> 8) : 0;
    int f_hi = t >> 8;
    if (f_hi > NF - 1) f_hi = NF - 1;

    float wt   = wav[t];
    float acc  = 0.0f;
    float wsum = 0.0f;

    #pragma unroll 4
    for (int f = f_lo; f <= f_hi; ++f) {
        int   j = t - (f << 8);                  // 0..1023
        float h = hann_t[j];                     // coalesced, L1/L2-hot
        int   e = enc_t[f];                      // wave-uniform-ish broadcast
        float val;
        if (e < 0) {
            val = wt;                            // unvoiced: frames path
        } else if (j < e) {
            float s  = scale_t[f];
            float x  = ((float)j + 0.5f) * s - 0.5f;
            x = fminf(fmaxf(x, 0.0f), 1023.0f);
            int   x0 = (int)floorf(x);
            int   x1 = x0 + 1; if (x1 > 1023) x1 = 1023;
            float w2 = x - (float)x0;
            const float* fr = wav + (f << 8);
            val = fr[x0] * (1.0f - w2) + fr[x1] * w2;
        } else {
            val = 0.0f;
        }
        acc  += val * h;
        wsum += h;
    }

    out[t] = (wsum > 1e-8f) ? (acc / wsum) : acc;
}

// Fallback (ws too small): self-contained, with the adaptive mask read.
__global__ __launch_bounds__(256) void psola_fallback(
    const float* __restrict__ wav,
    const float* __restrict__ src_f0,
    const float* __restrict__ tgt_f0,
    const unsigned int* __restrict__ mask_words,
    float*       __restrict__ out)
{
    bool bytelay = detect_byte_layout(mask_words, threadIdx.x);
    const unsigned char* m8 = (const unsigned char*)mask_words;

    int t = blockIdx.x * 256 + threadIdx.x;
    int a    = t - (FRAME_L - 1);
    int f_lo = (a > 0) ? ((a + HOP - 1) >> 8) : 0;
    int f_hi = t >> 8;
    if (f_hi > NF - 1) f_hi = NF - 1;

    float wt = wav[t], acc = 0.0f, wsum = 0.0f;
    for (int f = f_lo; f <= f_hi; ++f) {
        int   j = t - (f << 8);
        float h = 0.5f - 0.5f * cospif((float)j * (1.0f / 512.0f));
        float src = src_f0[f], tgt = tgt_f0[f];
        unsigned off = bytelay ? (unsigned)f : ((unsigned)f << 2);
        bool valid = (m8[off] != 0) && (src >= 1.0f) && (tgt >= 1.0f);
        float val;
        if (valid) {
            float denom = (tgt >= 1.0f) ? tgt : 1.0f;
            float ratio = fminf(fmaxf(src / denom, 0.25f), 4.0f);
            int nl = (int)rintf(1024.0f * ratio);
            if (nl < 1) nl = 1;
            if (j < nl) {
                float s  = 1024.0f / (float)nl;
                float x  = fminf(fmaxf(((float)j + 0.5f) * s - 0.5f, 0.0f), 1023.0f);
                int   x0 = (int)floorf(x);
                int   x1 = x0 + 1; if (x1 > 1023) x1 = 1023;
                float w2 = x - (float)x0;
                const float* fr = wav + (f << 8);
                val = fr[x0] * (1.0f - w2) + fr[x1] * w2;
            } else val = 0.0f;
        } else val = wt;
        acc += val * h; wsum += h;
    }
    out[t] = (wsum > 1e-8f) ? (acc / wsum) : acc;
}

extern "C" void kernel_launch(void* const* d_in, const int* in_sizes, int n_in,
                              void* d_out, int out_size, void* d_ws, size_t ws_size,
                              hipStream_t stream) {
    const float*        wav  = (const float*)d_in[0];
    const float*        src  = (const float*)d_in[1];
    const float*        tgt  = (const float*)d_in[2];
    const unsigned int* mask = (const unsigned int*)d_in[3];
    float*              out  = (float*)d_out;

    const size_t need = (1024 + 32768 + 32768) * 4;   // hann + scale + enc
    if (ws_size >= need) {
        float* hann_t  = (float*)d_ws;
        float* scale_t = hann_t + 1024;
        int*   enc_t   = (int*)(scale_t + 32768);
        psola_prepass<<<128, 256, 0, stream>>>(src, tgt, mask, hann_t, scale_t, enc_t);
        psola_main<<<T_WAV / 256, 256, 0, stream>>>(wav, hann_t, scale_t, enc_t, out);
    } else {
        psola_fallback<<<T_WAV / 256, 256, 0, stream>>>(wav, src, tgt, mask, out);
    }
}

// Round 3
// 128.590 us; speedup vs baseline: 1.0496x; 1.0496x over previous
//
#include <hip/hip_runtime.h>
#include <math.h>

#define T_WAV    8388608
#define FRAME_L  1024
#define HOP      256
#define NF       32765   // (T_WAV - FRAME_L)/HOP + 1
#define NBLK     (T_WAV / 256)

// ---------------------------------------------------------------------------
// Mask layout detection (unchanged from R2 — it passed): pristine-restore may
// leave voiced_mask as int32 0/1 per frame or packed bool bytes. Reading one
// byte at (bytelay ? f : 4*f) is correct for both (little-endian low byte).
// ---------------------------------------------------------------------------
__device__ __forceinline__ bool detect_byte_layout(const unsigned int* mask_words,
                                                   int tid) {
    __shared__ int s_flag;
    if (tid == 0) s_flag = 0;
    __syncthreads();
    unsigned w = mask_words[tid & 255];
    if ((w & 0xFFFFFF00u) != 0u && w != 0xFFFFFFFFu) atomicOr(&s_flag, 1);
    __syncthreads();
    return s_flag != 0;
}

// Prepass: per-frame {enc = valid ? new_len : -1, scale} + hann[1024] table.
__global__ __launch_bounds__(256) void psola_prepass(
    const float* __restrict__ src_f0,
    const float* __restrict__ tgt_f0,
    const unsigned int* __restrict__ mask_words,
    float* __restrict__ hann_t,     // [1024]
    float* __restrict__ scale_t,    // [32768]
    int*   __restrict__ enc_t)      // [32768]
{
    bool bytelay = detect_byte_layout(mask_words, threadIdx.x);

    if (blockIdx.x == 0) {
        for (int k = threadIdx.x; k < 1024; k += 256)
            hann_t[k] = 0.5f - 0.5f * cospif((float)k * (1.0f / 512.0f));
    }

    int f = blockIdx.x * 256 + threadIdx.x;
    if (f < NF) {
        float src = src_f0[f];
        float tgt = tgt_f0[f];
        const unsigned char* m8 = (const unsigned char*)mask_words;
        unsigned off = bytelay ? (unsigned)f : ((unsigned)f << 2);
        int vm = m8[off];
        bool valid = (vm != 0) && (src >= 1.0f) && (tgt >= 1.0f);
        float denom = (tgt >= 1.0f) ? tgt : 1.0f;
        float ratio = fminf(fmaxf(src / denom, 0.25f), 4.0f);
        int nl = (int)rintf(1024.0f * ratio);    // round-half-even == jnp.round
        if (nl < 1) nl = 1;
        scale_t[f] = 1024.0f / (float)nl;
        enc_t[f]   = valid ? nl : -1;
    }
}

// Main: block b covers samples [b*256, b*256+256) = frames [max(0,b-3), min(b,NF-1)].
// Stage the 7 KB wav window + hann table into LDS; all gathers hit LDS.
__global__ __launch_bounds__(256) void psola_main_lds(
    const float* __restrict__ wav,
    const float* __restrict__ hann_t,
    const float* __restrict__ scale_t,
    const int*   __restrict__ enc_t,
    float*       __restrict__ out)
{
    __shared__ float s_wav[1792];   // up to 4 overlapping frames' union window
    __shared__ float s_hann[1024];
    __shared__ int   s_enc[4];
    __shared__ float s_scale[4];

    const int b   = blockIdx.x;
    const int tid = threadIdx.x;
    const int t   = (b << 8) + tid;

    const int f0   = (b > 3) ? (b - 3) : 0;
    const int f1   = (b < NF - 1) ? b : (NF - 1);
    const int base = f0 << 8;                    // window start (float index)
    const int wlen = ((f1 - f0) << 8) + 1024;    // window length, mult of 4, <=1792

    // coalesced float4 staging (window start is 1 KiB aligned; end <= T_WAV)
    {
        const float4* g4 = (const float4*)(wav + base);
        float4*       s4 = (float4*)s_wav;
        const int nv = wlen >> 2;                // <= 448
        for (int i = tid; i < nv; i += 256) s4[i] = g4[i];
    }
    ((float4*)s_hann)[tid] = ((const float4*)hann_t)[tid];
    if (tid < 4) {
        int f = f0 + tid;
        if (f <= f1) { s_enc[tid] = enc_t[f]; s_scale[tid] = scale_t[f]; }
    }
    __syncthreads();

    const int ltid = t - base;                   // wav[t]'s index in s_wav
    float acc = 0.0f, wsum = 0.0f;

    if (f0 == b - 3 && f1 == b) {
        // interior: exactly 4 frames, fully unrolled for ILP
        #pragma unroll
        for (int i = 0; i < 4; ++i) {
            int   j = ltid - (i << 8);           // 0..1023
            float h = s_hann[j];
            int   e = s_enc[i];                  // block-uniform branch
            float val;
            if (e < 0) {
                val = s_wav[ltid];               // unvoiced: original sample
            } else if (j < e) {
                float s  = s_scale[i];
                float x  = fminf(fmaxf(((float)j + 0.5f) * s - 0.5f, 0.0f), 1023.0f);
                int   x0 = (int)x;               // x >= 0 -> trunc == floor
                int   x1 = (x0 < 1023) ? x0 + 1 : 1023;
                float w2 = x - (float)x0;
                float v0 = s_wav[(i << 8) + x0];
                float v1 = s_wav[(i << 8) + x1];
                val = v0 * (1.0f - w2) + v1 * w2;
            } else {
                val = 0.0f;
            }
            acc  += val * h;
            wsum += h;
        }
    } else {
        // edge blocks (b<3 or b>NF-1): generic frame loop
        for (int f = f0; f <= f1; ++f) {
            int   i = f - f0;
            int   j = t - (f << 8);
            float h = s_hann[j];
            int   e = s_enc[i];
            float val;
            if (e < 0) {
                val = s_wav[ltid];
            } else if (j < e) {
                float s  = s_scale[i];
                float x  = fminf(fmaxf(((float)j + 0.5f) * s - 0.5f, 0.0f), 1023.0f);
                int   x0 = (int)x;
                int   x1 = (x0 < 1023) ? x0 + 1 : 1023;
                float w2 = x - (float)x0;
                float v0 = s_wav[(i << 8) + x0];
                float v1 = s_wav[(i << 8) + x1];
                val = v0 * (1.0f - w2) + v1 * w2;
            } else {
                val = 0.0f;
            }
            acc  += val * h;
            wsum += h;
        }
    }

    out[t] = (wsum > 1e-8f) ? (acc / wsum) : acc;
}

// Fallback (ws too small): self-contained, with the adaptive mask read.
__global__ __launch_bounds__(256) void psola_fallback(
    const float* __restrict__ wav,
    const float* __restrict__ src_f0,
    const float* __restrict__ tgt_f0,
    const unsigned int* __restrict__ mask_words,
    float*       __restrict__ out)
{
    bool bytelay = detect_byte_layout(mask_words, threadIdx.x);
    const unsigned char* m8 = (const unsigned char*)mask_words;

    int t = blockIdx.x * 256 + threadIdx.x;
    int a    = t - (FRAME_L - 1);
    int f_lo = (a > 0) ? ((a + HOP - 1) >> 8) : 0;
    int f_hi = t >> 8;
    if (f_hi > NF - 1) f_hi = NF - 1;

    float wt = wav[t], acc = 0.0f, wsum = 0.0f;
    for (int f = f_lo; f <= f_hi; ++f) {
        int   j = t - (f << 8);
        float h = 0.5f - 0.5f * cospif((float)j * (1.0f / 512.0f));
        float src = src_f0[f], tgt = tgt_f0[f];
        unsigned off = bytelay ? (unsigned)f : ((unsigned)f << 2);
        bool valid = (m8[off] != 0) && (src >= 1.0f) && (tgt >= 1.0f);
        float val;
        if (valid) {
            float denom = (tgt >= 1.0f) ? tgt : 1.0f;
            float ratio = fminf(fmaxf(src / denom, 0.25f), 4.0f);
            int nl = (int)rintf(1024.0f * ratio);
            if (nl < 1) nl = 1;
            if (j < nl) {
                float s  = 1024.0f / (float)nl;
                float x  = fminf(fmaxf(((float)j + 0.5f) * s - 0.5f, 0.0f), 1023.0f);
                int   x0 = (int)floorf(x);
                int   x1 = x0 + 1; if (x1 > 1023) x1 = 1023;
                float w2 = x - (float)x0;
                const float* fr = wav + (f << 8);
                val = fr[x0] * (1.0f - w2) + fr[x1] * w2;
            } else val = 0.0f;
        } else val = wt;
        acc += val * h; wsum += h;
    }
    out[t] = (wsum > 1e-8f) ? (acc / wsum) : acc;
}

extern "C" void kernel_launch(void* const* d_in, const int* in_sizes, int n_in,
                              void* d_out, int out_size, void* d_ws, size_t ws_size,
                              hipStream_t stream) {
    const float*        wav  = (const float*)d_in[0];
    const float*        src  = (const float*)d_in[1];
    const float*        tgt  = (const float*)d_in[2];
    const unsigned int* mask = (const unsigned int*)d_in[3];
    float*              out  = (float*)d_out;

    const size_t need = (1024 + 32768 + 32768) * 4;   // hann + scale + enc
    if (ws_size >= need) {
        float* hann_t  = (float*)d_ws;
        float* scale_t = hann_t + 1024;
        int*   enc_t   = (int*)(scale_t + 32768);
        psola_prepass<<<128, 256, 0, stream>>>(src, tgt, mask, hann_t, scale_t, enc_t);
        psola_main_lds<<<NBLK, 256, 0, stream>>>(wav, hann_t, scale_t, enc_t, out);
    } else {
        psola_fallback<<<T_WAV / 256, 256, 0, stream>>>(wav, src, tgt, mask, out);
    }
}

// Round 4
// 99.528 us; speedup vs baseline: 1.3561x; 1.2920x over previous
//
#include <hip/hip_runtime.h>
#include <math.h>

#define T_WAV    8388608
#define FRAME_L  1024
#define HOP      256
#define NF       32765        // (T_WAV - FRAME_L)/HOP + 1
#define NBLK4    (T_WAV / 1024)   // 8192 blocks, 4 hops (1024 outputs) each

// ---------------------------------------------------------------------------
// Mask layout detection (proven in R2/R3): pristine-restore may leave
// voiced_mask as int32 0/1 per frame or packed bool bytes. Reading one byte
// at (bytelay ? f : 4*f) is correct for both (little-endian low byte).
// ---------------------------------------------------------------------------
__device__ __forceinline__ bool detect_byte_layout(const unsigned int* mask_words,
                                                   int tid) {
    __shared__ int s_flag;
    if (tid == 0) s_flag = 0;
    __syncthreads();
    unsigned w = mask_words[tid & 255];
    if ((w & 0xFFFFFF00u) != 0u && w != 0xFFFFFFFFu) atomicOr(&s_flag, 1);
    __syncthreads();
    return s_flag != 0;
}

// Prepass: per-frame {enc = valid ? new_len : -1, scale}.
__global__ __launch_bounds__(256) void psola_prepass(
    const float* __restrict__ src_f0,
    const float* __restrict__ tgt_f0,
    const unsigned int* __restrict__ mask_words,
    float* __restrict__ scale_t,    // [32768]
    int*   __restrict__ enc_t)      // [32768]
{
    bool bytelay = detect_byte_layout(mask_words, threadIdx.x);
    int f = blockIdx.x * 256 + threadIdx.x;
    if (f < NF) {
        float src = src_f0[f];
        float tgt = tgt_f0[f];
        const unsigned char* m8 = (const unsigned char*)mask_words;
        unsigned off = bytelay ? (unsigned)f : ((unsigned)f << 2);
        bool valid = (m8[off] != 0) && (src >= 1.0f) && (tgt >= 1.0f);
        float denom = (tgt >= 1.0f) ? tgt : 1.0f;
        float ratio = fminf(fmaxf(src / denom, 0.25f), 4.0f);
        int nl = (int)rintf(1024.0f * ratio);    // round-half-even == jnp.round
        if (nl < 1) nl = 1;
        scale_t[f] = 1024.0f / (float)nl;
        enc_t[f]   = valid ? nl : -1;
    }
}

// Main: logical block L covers outputs [1024L, 1024L+1024) = hops 4L..4L+3,
// needing frames [4L-3, 4L+3] -> window of 2560 floats (10 KB) in LDS.
// XCD swizzle: physical p -> L = (p&7)*1024 + (p>>3) so consecutive windows
// share one XCD's L2.
__global__ __launch_bounds__(256) void psola_main4(
    const float* __restrict__ wav,
    const float* __restrict__ scale_t,
    const int*   __restrict__ enc_t,
    float*       __restrict__ out)
{
    __shared__ float s_wav[2564];     // 2560 window + 1 pad (+align)

    const int p   = blockIdx.x;
    const int L   = ((p & 7) << 10) + (p >> 3);     // XCD-aware swizzle
    const int tid = threadIdx.x;
    const int B   = L << 10;                        // first output sample

    const int b0 = L << 2;                          // first hop index
    const int f0 = (b0 > 3) ? (b0 - 3) : 0;
    const int f1 = ((b0 + 3) < NF - 1) ? (b0 + 3) : (NF - 1);
    const int base = f0 << 8;
    const int wlen = ((f1 - f0) << 8) + 1024;       // <= 2560, mult of 4

    // coalesced float4 staging (base is 1 KiB aligned, end <= T_WAV)
    {
        const float4* g4 = (const float4*)(wav + base);
        float4*       s4 = (float4*)s_wav;
        const int nv = wlen >> 2;                   // <= 640
        for (int i = tid; i < nv; i += 256) s4[i] = g4[i];
    }
    if (tid == 0) s_wav[wlen] = 0.0f;               // pad for x0==1023 pair-read

    // per-frame params are block-uniform -> scalar loads into registers
    int   enc[7];
    float scl[7];
    #pragma unroll
    for (int i = 0; i < 7; ++i) {
        int f = f0 + i;
        if (f <= f1) { enc[i] = enc_t[f]; scl[i] = scale_t[f]; }
        else         { enc[i] = -1;       scl[i] = 1.0f; }
    }

    // each thread only ever needs hann at tid + 256*m, m=0..3
    float hh[4], jf[4];
    #pragma unroll
    for (int m = 0; m < 4; ++m) {
        int j = tid + (m << 8);
        hh[m] = 0.5f - 0.5f * cospif((float)j * (1.0f / 512.0f));
        jf[m] = (float)j + 0.5f;
    }
    float wsum4 = hh[0] + hh[1] + hh[2] + hh[3];
    float rw4   = (wsum4 > 1e-8f) ? (1.0f / wsum4) : 1.0f;

    __syncthreads();

    if (f0 == b0 - 3 && b0 + 3 <= NF - 1) {
        // interior block: every output has exactly 4 covering frames
        #pragma unroll
        for (int k = 0; k < 4; ++k) {
            const int loc_t = (k << 8) + tid + 768;     // index of t in s_wav
            float acc = 0.0f;
            #pragma unroll
            for (int q = 0; q < 4; ++q) {
                const int   fi = k + q;                 // frame f0+fi
                const int   e  = enc[fi];               // uniform branch
                const int   m  = 3 - q;                 // j = tid + m*256
                float val;
                if (e < 0) {
                    val = s_wav[loc_t];
                } else if ((tid + (m << 8)) < e) {
                    float s  = scl[fi];
                    float x  = fminf(fmaxf(fmaf(jf[m], s, -0.5f), 0.0f), 1023.0f);
                    int   x0 = (int)x;
                    float w2 = x - (float)x0;
                    const float* pp = &s_wav[(fi << 8) + x0];
                    float v0 = pp[0];
                    float v1 = pp[1];                   // ds_read2; pad-safe, w2==0 at edge
                    val = fmaf(w2, v1 - v0, v0);
                } else {
                    val = 0.0f;
                }
                acc = fmaf(val, hh[m], acc);
            }
            out[B + (k << 8) + tid] = acc * rw4;
        }
    } else {
        // edge blocks (L==0 or last): generic clamped frame loop
        for (int k = 0; k < 4; ++k) {
            const int t  = B + (k << 8) + tid;
            const int bt = t >> 8;
            int lo = bt - 3; if (lo < 0) lo = 0;
            int hi = bt;     if (hi > NF - 1) hi = NF - 1;
            float acc = 0.0f, wsum = 0.0f;
            for (int f = lo; f <= hi; ++f) {
                const int fi = f - f0;
                const int j  = t - (f << 8);
                const int m  = j >> 8;
                const float h = hh[m];
                const int   e = enc[fi];
                float val;
                if (e < 0) {
                    val = s_wav[t - base];
                } else if (j < e) {
                    float s  = scl[fi];
                    float x  = fminf(fmaxf(fmaf(jf[m], s, -0.5f), 0.0f), 1023.0f);
                    int   x0 = (int)x;
                    float w2 = x - (float)x0;
                    const float* pp = &s_wav[(fi << 8) + x0];
                    float v0 = pp[0];
                    float v1 = pp[1];
                    val = fmaf(w2, v1 - v0, v0);
                } else {
                    val = 0.0f;
                }
                acc  = fmaf(val, h, acc);
                wsum += h;
            }
            out[t] = (wsum > 1e-8f) ? (acc / wsum) : acc;
        }
    }
}

// Fallback (ws too small): self-contained, adaptive mask read.
__global__ __launch_bounds__(256) void psola_fallback(
    const float* __restrict__ wav,
    const float* __restrict__ src_f0,
    const float* __restrict__ tgt_f0,
    const unsigned int* __restrict__ mask_words,
    float*       __restrict__ out)
{
    bool bytelay = detect_byte_layout(mask_words, threadIdx.x);
    const unsigned char* m8 = (const unsigned char*)mask_words;

    int t = blockIdx.x * 256 + threadIdx.x;
    int a    = t - (FRAME_L - 1);
    int f_lo = (a > 0) ? ((a + HOP - 1) >> 8) : 0;
    int f_hi = t >> 8;
    if (f_hi > NF - 1) f_hi = NF - 1;

    float wt = wav[t], acc = 0.0f, wsum = 0.0f;
    for (int f = f_lo; f <= f_hi; ++f) {
        int   j = t - (f << 8);
        float h = 0.5f - 0.5f * cospif((float)j * (1.0f / 512.0f));
        float src = src_f0[f], tgt = tgt_f0[f];
        unsigned off = bytelay ? (unsigned)f : ((unsigned)f << 2);
        bool valid = (m8[off] != 0) && (src >= 1.0f) && (tgt >= 1.0f);
        float val;
        if (valid) {
            float denom = (tgt >= 1.0f) ? tgt : 1.0f;
            float ratio = fminf(fmaxf(src / denom, 0.25f), 4.0f);
            int nl = (int)rintf(1024.0f * ratio);
            if (nl < 1) nl = 1;
            if (j < nl) {
                float s  = 1024.0f / (float)nl;
                float x  = fminf(fmaxf(((float)j + 0.5f) * s - 0.5f, 0.0f), 1023.0f);
                int   x0 = (int)floorf(x);
                int   x1 = x0 + 1; if (x1 > 1023) x1 = 1023;
                float w2 = x - (float)x0;
                const float* fr = wav + (f << 8);
                val = fr[x0] * (1.0f - w2) + fr[x1] * w2;
            } else val = 0.0f;
        } else val = wt;
        acc += val * h; wsum += h;
    }
    out[t] = (wsum > 1e-8f) ? (acc / wsum) : acc;
}

extern "C" void kernel_launch(void* const* d_in, const int* in_sizes, int n_in,
                              void* d_out, int out_size, void* d_ws, size_t ws_size,
                              hipStream_t stream) {
    const float*        wav  = (const float*)d_in[0];
    const float*        src  = (const float*)d_in[1];
    const float*        tgt  = (const float*)d_in[2];
    const unsigned int* mask = (const unsigned int*)d_in[3];
    float*              out  = (float*)d_out;

    const size_t need = (32768 + 32768) * 4;   // scale_t + enc_t
    if (ws_size >= need) {
        float* scale_t = (float*)d_ws;
        int*   enc_t   = (int*)(scale_t + 32768);
        psola_prepass<<<128, 256, 0, stream>>>(src, tgt, mask, scale_t, enc_t);
        psola_main4<<<NBLK4, 256, 0, stream>>>(wav, scale_t, enc_t, out);
    } else {
        psola_fallback<<<T_WAV / 256, 256, 0, stream>>>(wav, src, tgt, mask, out);
    }
}